// Round 13
// baseline (312.131 us; speedup 1.0000x reference)
//
#include <hip/hip_runtime.h>
#include <math.h>

typedef unsigned short bfu;
typedef __attribute__((ext_vector_type(8))) short bf16x8;
typedef __attribute__((ext_vector_type(16))) float f32x16;

__device__ __forceinline__ float b2f(bfu u) {
    unsigned int x = ((unsigned int)u) << 16;
    return __uint_as_float(x);
}
__device__ __forceinline__ bfu f2bf(float f) {
    unsigned int u = __float_as_uint(f);
    unsigned int r = (u + 0x7FFFu + ((u >> 16) & 1u)) >> 16;
    return (bfu)r;
}

// ---------------------------------------------------------------------------
// fused init: zeros (y=0) + 6 weight transposes to hi/lo (y=1..6) + x0 cvt (y=7)
// ---------------------------------------------------------------------------
struct InitArgs {
    int* deg; int N; int* cdeg; int NC; float* sumsq;
    const float* w[6]; bfu* whi[6]; bfu* wlo[6]; int K[6]; int Nw[6];
    const float* x0; bfu* xhi; bfu* xlo; int xtotal;
};

__global__ __launch_bounds__(256) void k_init(InitArgs a) {
    const int j = blockIdx.y;
    const int g0 = blockIdx.x * 256 + threadIdx.x;
    const int gs = gridDim.x * 256;
    if (j == 0) {
        for (int i = g0; i < a.N; i += gs) a.deg[i] = 0;
        for (int i = g0; i < a.NC; i += gs) a.cdeg[i] = 0;
        for (int i = g0; i < 512; i += gs) a.sumsq[i] = 0.f;
    } else if (j <= 6) {
        const int jj = j - 1;
        const int K = a.K[jj], Nw = a.Nw[jj];
        const int total = K * Nw;
        const float* w = a.w[jj];
        bfu* dhi = a.whi[jj];
        bfu* dlo = a.wlo[jj];
        for (int idx = g0; idx < total; idx += gs) {
            int k = idx / Nw, n = idx % Nw;
            float v = w[idx];
            bfu hi = f2bf(v);
            bfu lo = f2bf(v - b2f(hi));
            dhi[n * K + k] = hi;
            dlo[n * K + k] = lo;
        }
    } else {
        for (int i = g0; i * 4 < a.xtotal; i += gs) {
            int base = i * 4;
            float4 v = *(const float4*)&a.x0[base];
            ushort4 h, l;
            h.x = f2bf(v.x); l.x = f2bf(v.x - b2f(h.x));
            h.y = f2bf(v.y); l.y = f2bf(v.y - b2f(h.y));
            h.z = f2bf(v.z); l.z = f2bf(v.z - b2f(h.z));
            h.w = f2bf(v.w); l.w = f2bf(v.w - b2f(h.w));
            *(ushort4*)&a.xhi[base] = h;
            *(ushort4*)&a.xlo[base] = l;
        }
    }
}

// ---------------------------------------------------------------------------
// fused histograms, 4-deep ILP: edge-dst -> deg[N], cluster -> cdeg[NC]
// ---------------------------------------------------------------------------
__global__ void k_hist2(const int* __restrict__ dst, int E, int* __restrict__ deg,
                        const int* __restrict__ cluster, int N, int* __restrict__ cdeg) {
    const int base = blockIdx.x * 1024 + threadIdx.x;
#pragma unroll
    for (int u = 0; u < 4; u++) {
        int e = base + u * 256;
        if (e < E) atomicAdd(&deg[dst[e]], 1);
    }
#pragma unroll
    for (int u = 0; u < 4; u++) {
        int i = base + u * 256;
        if (i < N) atomicAdd(&cdeg[cluster[i]], 1);
    }
}

// Phase A: per-block inclusive scan; store inclusive + raw block sums.
__global__ __launch_bounds__(256) void k_scanA(const int* __restrict__ deg, int N,
                                               const int* __restrict__ cdeg, int NC,
                                               int* __restrict__ scn0, int* __restrict__ scn1,
                                               int* __restrict__ bsum0, int* __restrict__ bsum1) {
    __shared__ int part[256];
    const int seg = blockIdx.y;
    const int n = seg ? NC : N;
    const int* d = seg ? cdeg : deg;
    int* scn = seg ? scn1 : scn0;
    int* bs  = seg ? bsum1 : bsum0;
    const int b = blockIdx.x;
    if (b * 256 >= n) return;
    const int t = threadIdx.x;
    const int i = b * 256 + t;
    int v = (i < n) ? d[i] : 0;
    part[t] = v;
    __syncthreads();
#pragma unroll
    for (int off = 1; off < 256; off <<= 1) {
        int cv = part[t];
        int u = (t >= off) ? part[t - off] : 0;
        __syncthreads();
        part[t] = cv + u;
        __syncthreads();
    }
    if (i < n) scn[i] = part[t];
    if (t == 255) bs[b] = part[255];
}

// Phase C: each block scans the (<=256) raw block sums in LDS, then
// ptr[i] = blockoff + incl[i] - d[i]; block 0 writes the total.
__global__ __launch_bounds__(256) void k_scanC(const int* __restrict__ deg, int N,
                                               const int* __restrict__ cdeg, int NC,
                                               const int* __restrict__ scn0, const int* __restrict__ scn1,
                                               const int* __restrict__ bsum0, int nb0,
                                               const int* __restrict__ bsum1, int nb1,
                                               int* __restrict__ ptr0, int* __restrict__ cur0,
                                               int* __restrict__ ptr1, int* __restrict__ cur1) {
    __shared__ int part[256];
    const int seg = blockIdx.y;
    const int n = seg ? NC : N;
    const int nb = seg ? nb1 : nb0;
    const int* d = seg ? cdeg : deg;
    const int* scn = seg ? scn1 : scn0;
    const int* bsum = seg ? bsum1 : bsum0;
    int* ptr = seg ? ptr1 : ptr0;
    int* cur = seg ? cur1 : cur0;
    const int b = blockIdx.x;
    if (b * 256 >= n) return;
    const int t = threadIdx.x;
    int v = (t < nb) ? bsum[t] : 0;
    part[t] = v;
    __syncthreads();
#pragma unroll
    for (int off = 1; off < 256; off <<= 1) {
        int cv = part[t];
        int u = (t >= off) ? part[t - off] : 0;
        __syncthreads();
        part[t] = cv + u;
        __syncthreads();
    }
    const int boff = (b == 0) ? 0 : part[b - 1];
    const int i = b * 256 + t;
    if (i < n) {
        int e = boff + scn[i] - d[i];
        ptr[i] = e;
        cur[i] = e;
    }
    if (b == 0 && t == 0) ptr[n] = part[nb - 1];
}

// ---------------------------------------------------------------------------
// LDS XOR-swizzle: byte ^= (row&7)<<4 (rows are 128B).
// ---------------------------------------------------------------------------
__device__ __forceinline__ int swz(int row, int kb) {
    return (row * 128 + (kb ^ ((row & 7) << 4))) >> 1;  // ushort index
}

// ---------------------------------------------------------------------------
// Fused layer-0 + scatters. Blocks [0,Mt): layer-0 GEMM pair (WLO=true).
// Blocks [Mt, Mt+Sc): 4-deep-ILP scatters (edges->colidx, nodes->cidx).
// The two halves write disjoint buffers; both only feed k_agg<1> and later.
// ---------------------------------------------------------------------------
__global__ __launch_bounds__(256) void k_l0scat(const bfu* __restrict__ Ahi, const bfu* __restrict__ Alo,
                                                const bfu* __restrict__ W1hi, const bfu* __restrict__ W1lo,
                                                const float* __restrict__ b1,
                                                const bfu* __restrict__ W2hi, const bfu* __restrict__ W2lo,
                                                const float* __restrict__ b2,
                                                bfu* __restrict__ Ohi, bfu* __restrict__ Olo,
                                                int M, int Mt,
                                                const int* __restrict__ dst, const int* __restrict__ src, int E,
                                                int* __restrict__ cur, int* __restrict__ colidx,
                                                const int* __restrict__ cluster,
                                                int* __restrict__ ccur, int* __restrict__ cidx) {
    __shared__ __align__(16) bfu As[2][64 * 64];
    __shared__ __align__(16) bfu Bs[2][64 * 64];
    const int tid = threadIdx.x;

    if (blockIdx.x >= Mt) {
        // ---------------- scatter path ----------------
        const int base = (blockIdx.x - Mt) * 1024 + tid;
#pragma unroll
        for (int u = 0; u < 4; u++) {
            int e = base + u * 256;
            if (e < E) {
                int d = dst[e];
                int pos = atomicAdd(&cur[d], 1);
                colidx[pos] = src[e];
            }
        }
#pragma unroll
        for (int u = 0; u < 4; u++) {
            int i = base + u * 256;
            if (i < M) {   // M == N nodes
                int c = cluster[i];
                int pos = atomicAdd(&ccur[c], 1);
                cidx[pos] = i;
            }
        }
        return;
    }

    // ---------------- layer-0 path (K=64, Kzero=64, Nw2=64, OS=128, WLO) ----
    const int K = 64, Nw2 = 64, OS = 128;
    const int wave = tid >> 6, lane = tid & 63;
    const int m0 = blockIdx.x * 64;
    const int l31 = lane & 31;
    const int khalfb = (lane >> 5) * 16;
    const int arow = (wave & 1) * 32 + l31;
    const int cbase = (wave >> 1) * 32;

    f32x16 acc;
#pragma unroll
    for (int i = 0; i < 16; i++) acc[i] = 0.f;

    {
        const int k0 = 0;
#pragma unroll
        for (int i = 0; i < 2; i++) {
            int idx = i * 2048 + tid * 8;
            int row = idx >> 6;
            int ke = idx & 63;
            int gm = m0 + row; if (gm >= M) gm = M - 1;
            uint4 v = *(const uint4*)&Ahi[(size_t)gm * K + k0 + ke];
            *(uint4*)&As[0][swz(row, ke * 2)] = v;
        }
#pragma unroll
        for (int i = 0; i < 2; i++) {
            int idx = i * 2048 + tid * 8;
            int row = idx >> 6;
            int ke = idx & 63;
            int gm = m0 + row; if (gm >= M) gm = M - 1;
            uint4 v = *(const uint4*)&Alo[(size_t)gm * K + k0 + ke];
            *(uint4*)&As[1][swz(row, ke * 2)] = v;
        }
#pragma unroll
        for (int p = 0; p < 2; p++) {
            const bfu* srcw = p ? W1lo : W1hi;
#pragma unroll
            for (int i = 0; i < 2; i++) {
                int idx = i * 2048 + tid * 8;
                int row = idx >> 6;
                int ke = idx & 63;
                uint4 v = *(const uint4*)&srcw[(size_t)row * K + k0 + ke];
                *(uint4*)&Bs[p][swz(row, ke * 2)] = v;
            }
        }
        __syncthreads();
#pragma unroll
        for (int s = 0; s < 4; s++) {
            int kb = s * 32 + khalfb;
            bf16x8 ah = *(const bf16x8*)&As[0][swz(arow, kb)];
            bf16x8 bh = *(const bf16x8*)&Bs[0][swz(cbase + l31, kb)];
            bf16x8 bl = *(const bf16x8*)&Bs[1][swz(cbase + l31, kb)];
            bf16x8 al = *(const bf16x8*)&As[1][swz(arow, kb)];
            acc = __builtin_amdgcn_mfma_f32_32x32x16_bf16(ah, bh, acc, 0, 0, 0);
            acc = __builtin_amdgcn_mfma_f32_32x32x16_bf16(ah, bl, acc, 0, 0, 0);
            acc = __builtin_amdgcn_mfma_f32_32x32x16_bf16(al, bh, acc, 0, 0, 0);
        }
        __syncthreads();
    }

    {
        float bc = b1[cbase + l31];
        const int rbase = (wave & 1) * 32 + 4 * (lane >> 5);
#pragma unroll
        for (int r = 0; r < 16; r++) {
            int row = rbase + (r & 3) + 8 * (r >> 2);
            float t0 = fmaxf(acc[r] + bc, 0.f);
            bfu h0 = f2bf(t0);
            bfu l0 = f2bf(t0 - b2f(h0));
            As[0][swz(row, (cbase + l31) * 2)] = h0;
            As[1][swz(row, (cbase + l31) * 2)] = l0;
        }
    }

    for (int n0 = 0; n0 < Nw2; n0 += 64) {
        __syncthreads();
#pragma unroll
        for (int p = 0; p < 2; p++) {
            const bfu* srcw = p ? W2lo : W2hi;
#pragma unroll
            for (int i = 0; i < 2; i++) {
                int idx = i * 2048 + tid * 8;
                int row = idx >> 6;
                int ke = idx & 63;
                uint4 v = *(const uint4*)&srcw[(size_t)(n0 + row) * 64 + ke];
                *(uint4*)&Bs[p][swz(row, ke * 2)] = v;
            }
        }
        __syncthreads();
#pragma unroll
        for (int i = 0; i < 16; i++) acc[i] = 0.f;
#pragma unroll
        for (int s = 0; s < 4; s++) {
            int kb = s * 32 + khalfb;
            bf16x8 th = *(const bf16x8*)&As[0][swz(arow, kb)];
            bf16x8 tl = *(const bf16x8*)&As[1][swz(arow, kb)];
            bf16x8 wh = *(const bf16x8*)&Bs[0][swz(cbase + l31, kb)];
            bf16x8 wl = *(const bf16x8*)&Bs[1][swz(cbase + l31, kb)];
            acc = __builtin_amdgcn_mfma_f32_32x32x16_bf16(th, wh, acc, 0, 0, 0);
            acc = __builtin_amdgcn_mfma_f32_32x32x16_bf16(th, wl, acc, 0, 0, 0);
            acc = __builtin_amdgcn_mfma_f32_32x32x16_bf16(tl, wh, acc, 0, 0, 0);
        }
        float bc = b2[n0 + cbase + l31];
        const int rbase = m0 + (wave & 1) * 32 + 4 * (lane >> 5);
#pragma unroll
        for (int r = 0; r < 16; r++) {
            int grow = rbase + (r & 3) + 8 * (r >> 2);
            if (grow < M) {
                float o0 = acc[r] + bc;
                bfu h0 = f2bf(o0);
                size_t base = (size_t)grow * OS + n0 + cbase;
                Ohi[base + l31] = h0;
                Olo[base + l31] = f2bf(o0 - b2f(h0));
            }
        }
    }
}

// ---------------------------------------------------------------------------
// Fused layer (layers 1,2): T = relu(X@W1 + b1); O = T@W2 + b2
//   64-row x 64-col tile, 4 waves; wave w owns rows (w&1)*32, cols (w>>1)*32.
// ---------------------------------------------------------------------------
template <bool WLO>
__global__ __launch_bounds__(256) void k_layer(const bfu* __restrict__ Ahi, const bfu* __restrict__ Alo,
                                               const bfu* __restrict__ W1hi, const bfu* __restrict__ W1lo,
                                               const float* __restrict__ b1,
                                               const bfu* __restrict__ W2hi, const bfu* __restrict__ W2lo,
                                               const float* __restrict__ b2,
                                               bfu* __restrict__ Ohi, bfu* __restrict__ Olo,
                                               int M, int K, int Kzero, int Nw2, int OS) {
    __shared__ __align__(16) bfu As[2][64 * 64];
    __shared__ __align__(16) bfu Bs[2][64 * 64];
    const int tid = threadIdx.x;
    const int wave = tid >> 6, lane = tid & 63;
    const int m0 = blockIdx.x * 64;
    const int l31 = lane & 31;
    const int khalfb = (lane >> 5) * 16;
    const int arow = (wave & 1) * 32 + l31;
    const int cbase = (wave >> 1) * 32;

    f32x16 acc;
#pragma unroll
    for (int i = 0; i < 16; i++) acc[i] = 0.f;

    for (int k0 = 0; k0 < K; k0 += 64) {
        const bool full3 = (k0 < Kzero);
#pragma unroll
        for (int i = 0; i < 2; i++) {
            int idx = i * 2048 + tid * 8;
            int row = idx >> 6;
            int ke = idx & 63;
            int gm = m0 + row; if (gm >= M) gm = M - 1;
            uint4 v = *(const uint4*)&Ahi[(size_t)gm * K + k0 + ke];
            *(uint4*)&As[0][swz(row, ke * 2)] = v;
        }
        if (full3) {
#pragma unroll
            for (int i = 0; i < 2; i++) {
                int idx = i * 2048 + tid * 8;
                int row = idx >> 6;
                int ke = idx & 63;
                int gm = m0 + row; if (gm >= M) gm = M - 1;
                uint4 v = *(const uint4*)&Alo[(size_t)gm * K + k0 + ke];
                *(uint4*)&As[1][swz(row, ke * 2)] = v;
            }
        }
#pragma unroll
        for (int p = 0; p < 2; p++) {
            const bfu* src = p ? W1lo : W1hi;
#pragma unroll
            for (int i = 0; i < 2; i++) {
                int idx = i * 2048 + tid * 8;
                int row = idx >> 6;
                int ke = idx & 63;
                uint4 v = *(const uint4*)&src[(size_t)row * K + k0 + ke];
                *(uint4*)&Bs[p][swz(row, ke * 2)] = v;
            }
        }
        __syncthreads();
#pragma unroll
        for (int s = 0; s < 4; s++) {
            int kb = s * 32 + khalfb;
            bf16x8 ah = *(const bf16x8*)&As[0][swz(arow, kb)];
            bf16x8 bh = *(const bf16x8*)&Bs[0][swz(cbase + l31, kb)];
            bf16x8 bl = *(const bf16x8*)&Bs[1][swz(cbase + l31, kb)];
            acc = __builtin_amdgcn_mfma_f32_32x32x16_bf16(ah, bh, acc, 0, 0, 0);
            acc = __builtin_amdgcn_mfma_f32_32x32x16_bf16(ah, bl, acc, 0, 0, 0);
            if (full3) {
                bf16x8 al = *(const bf16x8*)&As[1][swz(arow, kb)];
                acc = __builtin_amdgcn_mfma_f32_32x32x16_bf16(al, bh, acc, 0, 0, 0);
            }
        }
        __syncthreads();
    }

    {
        float bc = b1[cbase + l31];
        const int rbase = (wave & 1) * 32 + 4 * (lane >> 5);
#pragma unroll
        for (int r = 0; r < 16; r++) {
            int row = rbase + (r & 3) + 8 * (r >> 2);
            float t0 = fmaxf(acc[r] + bc, 0.f);
            bfu h0 = f2bf(t0);
            bfu l0 = f2bf(t0 - b2f(h0));
            As[0][swz(row, (cbase + l31) * 2)] = h0;
            As[1][swz(row, (cbase + l31) * 2)] = l0;
        }
    }

    for (int n0 = 0; n0 < Nw2; n0 += 64) {
        __syncthreads();
#pragma unroll
        for (int p = 0; p < 2; p++) {
            const bfu* src = p ? W2lo : W2hi;
#pragma unroll
            for (int i = 0; i < 2; i++) {
                int idx = i * 2048 + tid * 8;
                int row = idx >> 6;
                int ke = idx & 63;
                uint4 v = *(const uint4*)&src[(size_t)(n0 + row) * 64 + ke];
                *(uint4*)&Bs[p][swz(row, ke * 2)] = v;
            }
        }
        __syncthreads();
#pragma unroll
        for (int i = 0; i < 16; i++) acc[i] = 0.f;
#pragma unroll
        for (int s = 0; s < 4; s++) {
            int kb = s * 32 + khalfb;
            bf16x8 th = *(const bf16x8*)&As[0][swz(arow, kb)];
            bf16x8 tl = *(const bf16x8*)&As[1][swz(arow, kb)];
            bf16x8 wh = *(const bf16x8*)&Bs[0][swz(cbase + l31, kb)];
            bf16x8 wl = *(const bf16x8*)&Bs[1][swz(cbase + l31, kb)];
            acc = __builtin_amdgcn_mfma_f32_32x32x16_bf16(th, wh, acc, 0, 0, 0);
            acc = __builtin_amdgcn_mfma_f32_32x32x16_bf16(th, wl, acc, 0, 0, 0);
            acc = __builtin_amdgcn_mfma_f32_32x32x16_bf16(tl, wh, acc, 0, 0, 0);
        }
        float bc = b2[n0 + cbase + l31];
        const int rbase = m0 + (wave & 1) * 32 + 4 * (lane >> 5);
#pragma unroll
        for (int r = 0; r < 16; r++) {
            int grow = rbase + (r & 3) + 8 * (r >> 2);
            if (grow < M) {
                float o0 = acc[r] + bc;
                bfu h0 = f2bf(o0);
                size_t base = (size_t)grow * OS + n0 + cbase;
                Ohi[base + l31] = h0;
                if (WLO) {
                    Olo[base + l31] = f2bf(o0 - b2f(h0));
                }
            }
        }
    }
}

// ---------------------------------------------------------------------------
// Aggregation: per-node max over incoming edges (CSR), wave per node.
// 8-deep ILP, 32-bit addressing. Gather cols [0,64R) of hi plane; write bf16
// max into cols [64R,128R). (R8/R10-proven form.)
// ---------------------------------------------------------------------------
template <int R>
__device__ __forceinline__ void gmax(const bfu* __restrict__ p, float* acc) {
    if (R == 4) {
        ushort4 v = *(const ushort4*)p;
        acc[0] = fmaxf(acc[0], b2f(v.x)); acc[1] = fmaxf(acc[1], b2f(v.y));
        acc[2] = fmaxf(acc[2], b2f(v.z)); acc[3] = fmaxf(acc[3], b2f(v.w));
    } else if (R == 2) {
        ushort2 v = *(const ushort2*)p;
        acc[0] = fmaxf(acc[0], b2f(v.x)); acc[1] = fmaxf(acc[1], b2f(v.y));
    } else {
        acc[0] = fmaxf(acc[0], b2f(*p));
    }
}

template <int R>
__global__ void k_agg(const bfu* __restrict__ hplane, bfu* __restrict__ whi,
                      const int* __restrict__ rowptr, const int* __restrict__ colidx,
                      int N, int stride) {
    const int wid = (blockIdx.x * blockDim.x + threadIdx.x) >> 6;
    const int lane = threadIdx.x & 63;
    if (wid >= N) return;
    const int beg = rowptr[wid], end = rowptr[wid + 1];
    const int ch = lane * R;

    float acc[R];
#pragma unroll
    for (int r = 0; r < R; r++) acc[r] = -INFINITY;

    int i = beg;
    for (; i + 8 <= end; i += 8) {
        int off[8];
#pragma unroll
        for (int u = 0; u < 8; u++) off[u] = colidx[i + u] * stride + ch;
#pragma unroll
        for (int u = 0; u < 8; u++) gmax<R>(hplane + off[u], acc);
    }
    for (; i + 2 <= end; i += 2) {
        int o0 = colidx[i] * stride + ch;
        int o1 = colidx[i + 1] * stride + ch;
        gmax<R>(hplane + o0, acc);
        gmax<R>(hplane + o1, acc);
    }
    if (i < end) gmax<R>(hplane + colidx[i] * stride + ch, acc);

    if (beg == end) {
#pragma unroll
        for (int r = 0; r < R; r++) acc[r] = 0.f;
    }
    int obase = wid * stride + 64 * R + ch;
#pragma unroll
    for (int r = 0; r < R; r++) whi[obase + r] = f2bf(acc[r]);
}

// ---------------------------------------------------------------------------
// Cluster max-pool from hi plane [M][512] only.
// ---------------------------------------------------------------------------
__global__ void k_pool(const bfu* __restrict__ xhi,
                       const int* __restrict__ cptr, const int* __restrict__ cidx,
                       float* __restrict__ pooled) {
    int cl = blockIdx.x;
    int tid = threadIdx.x;
    int beg = cptr[cl], end = cptr[cl + 1];
    float ax = -INFINITY, ay = -INFINITY;
    int i = beg;
    for (; i + 4 <= end; i += 4) {
        ushort2 h0 = *(const ushort2*)&xhi[cidx[i + 0] * 512 + tid * 2];
        ushort2 h1 = *(const ushort2*)&xhi[cidx[i + 1] * 512 + tid * 2];
        ushort2 h2 = *(const ushort2*)&xhi[cidx[i + 2] * 512 + tid * 2];
        ushort2 h3 = *(const ushort2*)&xhi[cidx[i + 3] * 512 + tid * 2];
        ax = fmaxf(ax, fmaxf(fmaxf(b2f(h0.x), b2f(h1.x)), fmaxf(b2f(h2.x), b2f(h3.x))));
        ay = fmaxf(ay, fmaxf(fmaxf(b2f(h0.y), b2f(h1.y)), fmaxf(b2f(h2.y), b2f(h3.y))));
    }
    for (; i < end; i++) {
        ushort2 h = *(const ushort2*)&xhi[cidx[i] * 512 + tid * 2];
        ax = fmaxf(ax, b2f(h.x)); ay = fmaxf(ay, b2f(h.y));
    }
    if (beg == end) { ax = 0.f; ay = 0.f; }
    float2 o; o.x = ax; o.y = ay;
    *(float2*)&pooled[(size_t)cl * 512 + tid * 2] = o;
}

// ---------------------------------------------------------------------------
// Column-wise sum of squares (axis 0), low-contention (64 blocks)
// ---------------------------------------------------------------------------
__global__ void k_sumsq(const float* __restrict__ pooled, float* __restrict__ sumsq, int NC) {
    int tid = threadIdx.x;
    float ax = 0.f, ay = 0.f;
    for (int r = blockIdx.x; r < NC; r += gridDim.x) {
        float2 v = *(const float2*)&pooled[(size_t)r * 512 + tid * 2];
        ax += v.x * v.x; ay += v.y * v.y;
    }
    atomicAdd(&sumsq[tid * 2 + 0], ax);
    atomicAdd(&sumsq[tid * 2 + 1], ay);
}

__global__ void k_scale(const float* __restrict__ pooled, const float* __restrict__ sumsq,
                        float* __restrict__ out, int total) {
    int i = blockIdx.x * blockDim.x + threadIdx.x;
    int base = i * 4;
    if (base < total) {
        float4 v = *(const float4*)&pooled[base];
        int col = base & 511;
        v.x /= (sqrtf(sumsq[col + 0]) + 1e-6f);
        v.y /= (sqrtf(sumsq[col + 1]) + 1e-6f);
        v.z /= (sqrtf(sumsq[col + 2]) + 1e-6f);
        v.w /= (sqrtf(sumsq[col + 3]) + 1e-6f);
        *(float4*)&out[base] = v;
    }
}

// ---------------------------------------------------------------------------
extern "C" void kernel_launch(void* const* d_in, const int* in_sizes, int n_in,
                              void* d_out, int out_size, void* d_ws, size_t ws_size,
                              hipStream_t stream) {
    const float* x0      = (const float*)d_in[0];
    const int*   ei      = (const int*)d_in[1];
    const int*   cluster = (const int*)d_in[2];
    const float* w1_[3] = {(const float*)d_in[3], (const float*)d_in[7],  (const float*)d_in[11]};
    const float* b1_[3] = {(const float*)d_in[4], (const float*)d_in[8],  (const float*)d_in[12]};
    const float* w2_[3] = {(const float*)d_in[5], (const float*)d_in[9],  (const float*)d_in[13]};
    const float* b2_[3] = {(const float*)d_in[6], (const float*)d_in[10], (const float*)d_in[14]};

    const int N  = in_sizes[2];       // 50000
    const int E  = in_sizes[1] / 2;   // 800000
    const int NC = 2500;
    float* out = (float*)d_out;

    char* p = (char*)d_ws;
    auto alloc = [&](size_t bytes) -> char* {
        char* r = p;
        p += (bytes + 255) & ~(size_t)255;
        return r;
    };
    bfu* X0hi = (bfu*)alloc((size_t)N * 64 * 2);
    bfu* X0lo = (bfu*)alloc((size_t)N * 64 * 2);
    bfu* X1hi = (bfu*)alloc((size_t)N * 128 * 2);
    bfu* X1lo = (bfu*)alloc((size_t)N * 128 * 2);
    bfu* X2hi = (bfu*)alloc((size_t)N * 256 * 2);
    bfu* X2lo = (bfu*)alloc((size_t)N * 256 * 2);
    bfu* X3hi = (bfu*)alloc((size_t)N * 512 * 2);
    bfu* w1t_hi[3]; bfu* w1t_lo[3]; bfu* w2t_hi[3]; bfu* w2t_lo[3];
    const int Ks[3] = {64, 128, 256};
    for (int l = 0; l < 3; l++) {
        w1t_hi[l] = (bfu*)alloc((size_t)64 * Ks[l] * 2);
        w1t_lo[l] = (bfu*)alloc((size_t)64 * Ks[l] * 2);
        w2t_hi[l] = (bfu*)alloc((size_t)Ks[l] * 64 * 2);
        w2t_lo[l] = (bfu*)alloc((size_t)Ks[l] * 64 * 2);
    }
    float* pooled = (float*)alloc((size_t)NC * 512 * 4);
    float* sumsq  = (float*)alloc(512 * 4);
    int*   deg    = (int*)alloc((size_t)(N + 1) * 4);
    int*   rowptr = (int*)alloc((size_t)(N + 1) * 4);
    int*   cursor = (int*)alloc((size_t)(N + 1) * 4);
    int*   colidx = (int*)alloc((size_t)E * 4);
    int*   cdeg   = (int*)alloc((size_t)(NC + 1) * 4);
    int*   cptr   = (int*)alloc((size_t)(NC + 1) * 4);
    int*   ccur   = (int*)alloc((size_t)(NC + 1) * 4);
    int*   cidx   = (int*)alloc((size_t)N * 4);
    int*   scn0   = (int*)alloc((size_t)N * 4);
    int*   scn1   = (int*)alloc((size_t)NC * 4);
    int*   bsum0  = (int*)alloc(256 * 4);
    int*   bsum1  = (int*)alloc(256 * 4);

    const int* src = ei;
    const int* dst = ei + E;

    // fused init: zeros + weight transposes + x0 conversion
    InitArgs ia;
    ia.deg = deg; ia.N = N; ia.cdeg = cdeg; ia.NC = NC; ia.sumsq = sumsq;
    for (int l = 0; l < 3; l++) {
        ia.w[2 * l]     = w1_[l]; ia.whi[2 * l]     = w1t_hi[l]; ia.wlo[2 * l]     = w1t_lo[l];
        ia.K[2 * l]     = Ks[l];  ia.Nw[2 * l]      = 64;
        ia.w[2 * l + 1] = w2_[l]; ia.whi[2 * l + 1] = w2t_hi[l]; ia.wlo[2 * l + 1] = w2t_lo[l];
        ia.K[2 * l + 1] = 64;     ia.Nw[2 * l + 1]  = Ks[l];
    }
    ia.x0 = x0; ia.xhi = X0hi; ia.xlo = X0lo; ia.xtotal = N * 64;
    k_init<<<dim3(128, 8), 256, 0, stream>>>(ia);

    // fused histograms (4-deep ILP)
    k_hist2<<<(E + 1023) / 1024, 256, 0, stream>>>(dst, E, deg, cluster, N, cdeg);

    // hierarchical exclusive scan (2 phases; C scans block sums inline)
    const int nb0 = (N + 255) / 256;
    const int nb1 = (NC + 255) / 256;
    k_scanA<<<dim3(nb0, 2), 256, 0, stream>>>(deg, N, cdeg, NC, scn0, scn1, bsum0, bsum1);
    k_scanC<<<dim3(nb0, 2), 256, 0, stream>>>(deg, N, cdeg, NC, scn0, scn1, bsum0, nb0, bsum1, nb1,
                                              rowptr, cursor, cptr, ccur);

    const int Mt = (N + 63) / 64;
    const int Sc = (E + 1023) / 1024;
    const int aggBlocks = (N * 64 + 255) / 256;

    // fused: layer 0 (c=64) + scatters (disjoint outputs, both feed agg<1>)
    k_l0scat<<<Mt + Sc, 256, 0, stream>>>(X0hi, X0lo, w1t_hi[0], w1t_lo[0], b1_[0],
                                          w2t_hi[0], w2t_lo[0], b2_[0], X1hi, X1lo,
                                          N, Mt,
                                          dst, src, E, cursor, colidx,
                                          cluster, ccur, cidx);
    k_agg<1><<<aggBlocks, 256, 0, stream>>>(X1hi, X1hi, rowptr, colidx, N, 128);

    // layer 1: c=128  (Alo for k>=64 structurally zero)
    k_layer<true><<<Mt, 256, 0, stream>>>(X1hi, X1lo, w1t_hi[1], w1t_lo[1], b1_[1],
                                          w2t_hi[1], w2t_lo[1], b2_[1], X2hi, X2lo,
                                          N, 128, 64, 128, 256);
    k_agg<2><<<aggBlocks, 256, 0, stream>>>(X2hi, X2hi, rowptr, colidx, N, 256);

    // layer 2: c=256  (Alo for k>=128 structurally zero; X3 lo plane dropped)
    k_layer<false><<<Mt, 256, 0, stream>>>(X2hi, X2lo, w1t_hi[2], w1t_lo[2], b1_[2],
                                           w2t_hi[2], w2t_lo[2], b2_[2], X3hi, nullptr,
                                           N, 256, 128, 256, 512);
    k_agg<4><<<aggBlocks, 256, 0, stream>>>(X3hi, X3hi, rowptr, colidx, N, 512);

    // cluster max-pool + column norm
    k_pool<<<NC, 256, 0, stream>>>(X3hi, cptr, cidx, pooled);
    k_sumsq<<<64, 256, 0, stream>>>(pooled, sumsq, NC);
    k_scale<<<(out_size / 4 + 255) / 256, 256, 0, stream>>>(pooled, sumsq, out, out_size);
}

// Round 14
// 276.830 us; speedup vs baseline: 1.1275x; 1.1275x over previous
//
#include <hip/hip_runtime.h>
#include <math.h>

typedef unsigned short bfu;
typedef __attribute__((ext_vector_type(8))) short bf16x8;
typedef __attribute__((ext_vector_type(16))) float f32x16;

__device__ __forceinline__ float b2f(bfu u) {
    unsigned int x = ((unsigned int)u) << 16;
    return __uint_as_float(x);
}
__device__ __forceinline__ bfu f2bf(float f) {
    unsigned int u = __float_as_uint(f);
    unsigned int r = (u + 0x7FFFu + ((u >> 16) & 1u)) >> 16;
    return (bfu)r;
}

// ---------------------------------------------------------------------------
// fused init: zeros (y=0) + 6 weight transposes to hi/lo (y=1..6) + x0 cvt (y=7)
// ---------------------------------------------------------------------------
struct InitArgs {
    int* deg; int N; int* cdeg; int NC; float* sumsq;
    const float* w[6]; bfu* whi[6]; bfu* wlo[6]; int K[6]; int Nw[6];
    const float* x0; bfu* xhi; bfu* xlo; int xtotal;
};

__global__ __launch_bounds__(256) void k_init(InitArgs a) {
    const int j = blockIdx.y;
    const int g0 = blockIdx.x * 256 + threadIdx.x;
    const int gs = gridDim.x * 256;
    if (j == 0) {
        for (int i = g0; i < a.N; i += gs) a.deg[i] = 0;
        for (int i = g0; i < a.NC; i += gs) a.cdeg[i] = 0;
        for (int i = g0; i < 512; i += gs) a.sumsq[i] = 0.f;
    } else if (j <= 6) {
        const int jj = j - 1;
        const int K = a.K[jj], Nw = a.Nw[jj];
        const int total = K * Nw;
        const float* w = a.w[jj];
        bfu* dhi = a.whi[jj];
        bfu* dlo = a.wlo[jj];
        for (int idx = g0; idx < total; idx += gs) {
            int k = idx / Nw, n = idx % Nw;
            float v = w[idx];
            bfu hi = f2bf(v);
            bfu lo = f2bf(v - b2f(hi));
            dhi[n * K + k] = hi;
            dlo[n * K + k] = lo;
        }
    } else {
        for (int i = g0; i * 4 < a.xtotal; i += gs) {
            int base = i * 4;
            float4 v = *(const float4*)&a.x0[base];
            ushort4 h, l;
            h.x = f2bf(v.x); l.x = f2bf(v.x - b2f(h.x));
            h.y = f2bf(v.y); l.y = f2bf(v.y - b2f(h.y));
            h.z = f2bf(v.z); l.z = f2bf(v.z - b2f(h.z));
            h.w = f2bf(v.w); l.w = f2bf(v.w - b2f(h.w));
            *(ushort4*)&a.xhi[base] = h;
            *(ushort4*)&a.xlo[base] = l;
        }
    }
}

// ---------------------------------------------------------------------------
// rank-recording histograms: deg[dst]++ with per-edge rank stored coalesced;
// cdeg[cluster]++ with per-node rank. 4-deep ILP.
// ---------------------------------------------------------------------------
__global__ void k_rank(const int* __restrict__ dst, int E, int* __restrict__ deg,
                       int* __restrict__ rank,
                       const int* __restrict__ cluster, int N, int* __restrict__ cdeg,
                       int* __restrict__ crank) {
    const int base = blockIdx.x * 1024 + threadIdx.x;
#pragma unroll
    for (int u = 0; u < 4; u++) {
        int e = base + u * 256;
        if (e < E) rank[e] = atomicAdd(&deg[dst[e]], 1);
    }
#pragma unroll
    for (int u = 0; u < 4; u++) {
        int i = base + u * 256;
        if (i < N) crank[i] = atomicAdd(&cdeg[cluster[i]], 1);
    }
}

// Phase A: per-block inclusive scan; store inclusive + raw block sums.
__global__ __launch_bounds__(256) void k_scanA(const int* __restrict__ deg, int N,
                                               const int* __restrict__ cdeg, int NC,
                                               int* __restrict__ scn0, int* __restrict__ scn1,
                                               int* __restrict__ bsum0, int* __restrict__ bsum1) {
    __shared__ int part[256];
    const int seg = blockIdx.y;
    const int n = seg ? NC : N;
    const int* d = seg ? cdeg : deg;
    int* scn = seg ? scn1 : scn0;
    int* bs  = seg ? bsum1 : bsum0;
    const int b = blockIdx.x;
    if (b * 256 >= n) return;
    const int t = threadIdx.x;
    const int i = b * 256 + t;
    int v = (i < n) ? d[i] : 0;
    part[t] = v;
    __syncthreads();
#pragma unroll
    for (int off = 1; off < 256; off <<= 1) {
        int cv = part[t];
        int u = (t >= off) ? part[t - off] : 0;
        __syncthreads();
        part[t] = cv + u;
        __syncthreads();
    }
    if (i < n) scn[i] = part[t];
    if (t == 255) bs[b] = part[255];
}

// Phase C: each block scans the (<=256) raw block sums in LDS, then
// ptr[i] = blockoff + incl[i] - d[i]; block 0 writes the total.
__global__ __launch_bounds__(256) void k_scanC(const int* __restrict__ deg, int N,
                                               const int* __restrict__ cdeg, int NC,
                                               const int* __restrict__ scn0, const int* __restrict__ scn1,
                                               const int* __restrict__ bsum0, int nb0,
                                               const int* __restrict__ bsum1, int nb1,
                                               int* __restrict__ ptr0, int* __restrict__ ptr1) {
    __shared__ int part[256];
    const int seg = blockIdx.y;
    const int n = seg ? NC : N;
    const int nb = seg ? nb1 : nb0;
    const int* d = seg ? cdeg : deg;
    const int* scn = seg ? scn1 : scn0;
    const int* bsum = seg ? bsum1 : bsum0;
    int* ptr = seg ? ptr1 : ptr0;
    const int b = blockIdx.x;
    if (b * 256 >= n) return;
    const int t = threadIdx.x;
    int v = (t < nb) ? bsum[t] : 0;
    part[t] = v;
    __syncthreads();
#pragma unroll
    for (int off = 1; off < 256; off <<= 1) {
        int cv = part[t];
        int u = (t >= off) ? part[t - off] : 0;
        __syncthreads();
        part[t] = cv + u;
        __syncthreads();
    }
    const int boff = (b == 0) ? 0 : part[b - 1];
    const int i = b * 256 + t;
    if (i < n) ptr[i] = boff + scn[i] - d[i];
    if (b == 0 && t == 0) ptr[n] = part[nb - 1];
}

// ---------------------------------------------------------------------------
// Atomic-free scatters: pos = ptr[key] + rank (precomputed). Coalesced reads,
// fire-and-forget scattered stores — no dependent RMW chains.
// ---------------------------------------------------------------------------
__global__ void k_scatter2(const int* __restrict__ dst, const int* __restrict__ src,
                           const int* __restrict__ rank, const int* __restrict__ rowptr,
                           int E, int* __restrict__ colidx,
                           const int* __restrict__ cluster, const int* __restrict__ crank,
                           const int* __restrict__ cptr, int N, int* __restrict__ cidx) {
    const int base = blockIdx.x * 1024 + threadIdx.x;
#pragma unroll
    for (int u = 0; u < 4; u++) {
        int e = base + u * 256;
        if (e < E) colidx[rowptr[dst[e]] + rank[e]] = src[e];
    }
#pragma unroll
    for (int u = 0; u < 4; u++) {
        int i = base + u * 256;
        if (i < N) cidx[cptr[cluster[i]] + crank[i]] = i;
    }
}

// ---------------------------------------------------------------------------
// LDS XOR-swizzle: byte ^= (row&7)<<4 (rows are 128B).
// ---------------------------------------------------------------------------
__device__ __forceinline__ int swz(int row, int kb) {
    return (row * 128 + (kb ^ ((row & 7) << 4))) >> 1;  // ushort index
}

// ---------------------------------------------------------------------------
// Fused layer: T = relu(X@W1 + b1); O = T@W2 + b2 (hi/lo bf16 planes)
//   64-row x 64-col tile, 4 waves; wave w owns rows (w&1)*32, cols (w>>1)*32.
// ---------------------------------------------------------------------------
template <bool WLO>
__global__ __launch_bounds__(256) void k_layer(const bfu* __restrict__ Ahi, const bfu* __restrict__ Alo,
                                               const bfu* __restrict__ W1hi, const bfu* __restrict__ W1lo,
                                               const float* __restrict__ b1,
                                               const bfu* __restrict__ W2hi, const bfu* __restrict__ W2lo,
                                               const float* __restrict__ b2,
                                               bfu* __restrict__ Ohi, bfu* __restrict__ Olo,
                                               int M, int K, int Kzero, int Nw2, int OS) {
    __shared__ __align__(16) bfu As[2][64 * 64];
    __shared__ __align__(16) bfu Bs[2][64 * 64];
    const int tid = threadIdx.x;
    const int wave = tid >> 6, lane = tid & 63;
    const int m0 = blockIdx.x * 64;
    const int l31 = lane & 31;
    const int khalfb = (lane >> 5) * 16;
    const int arow = (wave & 1) * 32 + l31;
    const int cbase = (wave >> 1) * 32;

    f32x16 acc;
#pragma unroll
    for (int i = 0; i < 16; i++) acc[i] = 0.f;

    for (int k0 = 0; k0 < K; k0 += 64) {
        const bool full3 = (k0 < Kzero);
#pragma unroll
        for (int i = 0; i < 2; i++) {
            int idx = i * 2048 + tid * 8;
            int row = idx >> 6;
            int ke = idx & 63;
            int gm = m0 + row; if (gm >= M) gm = M - 1;
            uint4 v = *(const uint4*)&Ahi[(size_t)gm * K + k0 + ke];
            *(uint4*)&As[0][swz(row, ke * 2)] = v;
        }
        if (full3) {
#pragma unroll
            for (int i = 0; i < 2; i++) {
                int idx = i * 2048 + tid * 8;
                int row = idx >> 6;
                int ke = idx & 63;
                int gm = m0 + row; if (gm >= M) gm = M - 1;
                uint4 v = *(const uint4*)&Alo[(size_t)gm * K + k0 + ke];
                *(uint4*)&As[1][swz(row, ke * 2)] = v;
            }
        }
#pragma unroll
        for (int p = 0; p < 2; p++) {
            const bfu* src = p ? W1lo : W1hi;
#pragma unroll
            for (int i = 0; i < 2; i++) {
                int idx = i * 2048 + tid * 8;
                int row = idx >> 6;
                int ke = idx & 63;
                uint4 v = *(const uint4*)&src[(size_t)row * K + k0 + ke];
                *(uint4*)&Bs[p][swz(row, ke * 2)] = v;
            }
        }
        __syncthreads();
#pragma unroll
        for (int s = 0; s < 4; s++) {
            int kb = s * 32 + khalfb;
            bf16x8 ah = *(const bf16x8*)&As[0][swz(arow, kb)];
            bf16x8 bh = *(const bf16x8*)&Bs[0][swz(cbase + l31, kb)];
            bf16x8 bl = *(const bf16x8*)&Bs[1][swz(cbase + l31, kb)];
            acc = __builtin_amdgcn_mfma_f32_32x32x16_bf16(ah, bh, acc, 0, 0, 0);
            acc = __builtin_amdgcn_mfma_f32_32x32x16_bf16(ah, bl, acc, 0, 0, 0);
            if (full3) {
                bf16x8 al = *(const bf16x8*)&As[1][swz(arow, kb)];
                acc = __builtin_amdgcn_mfma_f32_32x32x16_bf16(al, bh, acc, 0, 0, 0);
            }
        }
        __syncthreads();
    }

    {
        float bc = b1[cbase + l31];
        const int rbase = (wave & 1) * 32 + 4 * (lane >> 5);
#pragma unroll
        for (int r = 0; r < 16; r++) {
            int row = rbase + (r & 3) + 8 * (r >> 2);
            float t0 = fmaxf(acc[r] + bc, 0.f);
            bfu h0 = f2bf(t0);
            bfu l0 = f2bf(t0 - b2f(h0));
            As[0][swz(row, (cbase + l31) * 2)] = h0;
            As[1][swz(row, (cbase + l31) * 2)] = l0;
        }
    }

    for (int n0 = 0; n0 < Nw2; n0 += 64) {
        __syncthreads();
#pragma unroll
        for (int p = 0; p < 2; p++) {
            const bfu* src = p ? W2lo : W2hi;
#pragma unroll
            for (int i = 0; i < 2; i++) {
                int idx = i * 2048 + tid * 8;
                int row = idx >> 6;
                int ke = idx & 63;
                uint4 v = *(const uint4*)&src[(size_t)(n0 + row) * 64 + ke];
                *(uint4*)&Bs[p][swz(row, ke * 2)] = v;
            }
        }
        __syncthreads();
#pragma unroll
        for (int i = 0; i < 16; i++) acc[i] = 0.f;
#pragma unroll
        for (int s = 0; s < 4; s++) {
            int kb = s * 32 + khalfb;
            bf16x8 th = *(const bf16x8*)&As[0][swz(arow, kb)];
            bf16x8 tl = *(const bf16x8*)&As[1][swz(arow, kb)];
            bf16x8 wh = *(const bf16x8*)&Bs[0][swz(cbase + l31, kb)];
            bf16x8 wl = *(const bf16x8*)&Bs[1][swz(cbase + l31, kb)];
            acc = __builtin_amdgcn_mfma_f32_32x32x16_bf16(th, wh, acc, 0, 0, 0);
            acc = __builtin_amdgcn_mfma_f32_32x32x16_bf16(th, wl, acc, 0, 0, 0);
            acc = __builtin_amdgcn_mfma_f32_32x32x16_bf16(tl, wh, acc, 0, 0, 0);
        }
        float bc = b2[n0 + cbase + l31];
        const int rbase = m0 + (wave & 1) * 32 + 4 * (lane >> 5);
#pragma unroll
        for (int r = 0; r < 16; r++) {
            int grow = rbase + (r & 3) + 8 * (r >> 2);
            if (grow < M) {
                float o0 = acc[r] + bc;
                bfu h0 = f2bf(o0);
                size_t base = (size_t)grow * OS + n0 + cbase;
                Ohi[base + l31] = h0;
                if (WLO) {
                    Olo[base + l31] = f2bf(o0 - b2f(h0));
                }
            }
        }
    }
}

// ---------------------------------------------------------------------------
// Aggregation: per-node max over incoming edges (CSR), wave per node.
// 8-deep ILP, 32-bit addressing. Gather cols [0,64R) of hi plane; write bf16
// max into cols [64R,128R). (R8/R10-proven form.)
// ---------------------------------------------------------------------------
template <int R>
__device__ __forceinline__ void gmax(const bfu* __restrict__ p, float* acc) {
    if (R == 4) {
        ushort4 v = *(const ushort4*)p;
        acc[0] = fmaxf(acc[0], b2f(v.x)); acc[1] = fmaxf(acc[1], b2f(v.y));
        acc[2] = fmaxf(acc[2], b2f(v.z)); acc[3] = fmaxf(acc[3], b2f(v.w));
    } else if (R == 2) {
        ushort2 v = *(const ushort2*)p;
        acc[0] = fmaxf(acc[0], b2f(v.x)); acc[1] = fmaxf(acc[1], b2f(v.y));
    } else {
        acc[0] = fmaxf(acc[0], b2f(*p));
    }
}

template <int R>
__global__ void k_agg(const bfu* __restrict__ hplane, bfu* __restrict__ whi,
                      const int* __restrict__ rowptr, const int* __restrict__ colidx,
                      int N, int stride) {
    const int wid = (blockIdx.x * blockDim.x + threadIdx.x) >> 6;
    const int lane = threadIdx.x & 63;
    if (wid >= N) return;
    const int beg = rowptr[wid], end = rowptr[wid + 1];
    const int ch = lane * R;

    float acc[R];
#pragma unroll
    for (int r = 0; r < R; r++) acc[r] = -INFINITY;

    int i = beg;
    for (; i + 8 <= end; i += 8) {
        int off[8];
#pragma unroll
        for (int u = 0; u < 8; u++) off[u] = colidx[i + u] * stride + ch;
#pragma unroll
        for (int u = 0; u < 8; u++) gmax<R>(hplane + off[u], acc);
    }
    for (; i + 2 <= end; i += 2) {
        int o0 = colidx[i] * stride + ch;
        int o1 = colidx[i + 1] * stride + ch;
        gmax<R>(hplane + o0, acc);
        gmax<R>(hplane + o1, acc);
    }
    if (i < end) gmax<R>(hplane + colidx[i] * stride + ch, acc);

    if (beg == end) {
#pragma unroll
        for (int r = 0; r < R; r++) acc[r] = 0.f;
    }
    int obase = wid * stride + 64 * R + ch;
#pragma unroll
    for (int r = 0; r < R; r++) whi[obase + r] = f2bf(acc[r]);
}

// ---------------------------------------------------------------------------
// Cluster max-pool from hi plane [M][512] only.
// ---------------------------------------------------------------------------
__global__ void k_pool(const bfu* __restrict__ xhi,
                       const int* __restrict__ cptr, const int* __restrict__ cidx,
                       float* __restrict__ pooled) {
    int cl = blockIdx.x;
    int tid = threadIdx.x;
    int beg = cptr[cl], end = cptr[cl + 1];
    float ax = -INFINITY, ay = -INFINITY;
    int i = beg;
    for (; i + 4 <= end; i += 4) {
        ushort2 h0 = *(const ushort2*)&xhi[cidx[i + 0] * 512 + tid * 2];
        ushort2 h1 = *(const ushort2*)&xhi[cidx[i + 1] * 512 + tid * 2];
        ushort2 h2 = *(const ushort2*)&xhi[cidx[i + 2] * 512 + tid * 2];
        ushort2 h3 = *(const ushort2*)&xhi[cidx[i + 3] * 512 + tid * 2];
        ax = fmaxf(ax, fmaxf(fmaxf(b2f(h0.x), b2f(h1.x)), fmaxf(b2f(h2.x), b2f(h3.x))));
        ay = fmaxf(ay, fmaxf(fmaxf(b2f(h0.y), b2f(h1.y)), fmaxf(b2f(h2.y), b2f(h3.y))));
    }
    for (; i < end; i++) {
        ushort2 h = *(const ushort2*)&xhi[cidx[i] * 512 + tid * 2];
        ax = fmaxf(ax, b2f(h.x)); ay = fmaxf(ay, b2f(h.y));
    }
    if (beg == end) { ax = 0.f; ay = 0.f; }
    float2 o; o.x = ax; o.y = ay;
    *(float2*)&pooled[(size_t)cl * 512 + tid * 2] = o;
}

// ---------------------------------------------------------------------------
// Column-wise sum of squares (axis 0), low-contention (64 blocks)
// ---------------------------------------------------------------------------
__global__ void k_sumsq(const float* __restrict__ pooled, float* __restrict__ sumsq, int NC) {
    int tid = threadIdx.x;
    float ax = 0.f, ay = 0.f;
    for (int r = blockIdx.x; r < NC; r += gridDim.x) {
        float2 v = *(const float2*)&pooled[(size_t)r * 512 + tid * 2];
        ax += v.x * v.x; ay += v.y * v.y;
    }
    atomicAdd(&sumsq[tid * 2 + 0], ax);
    atomicAdd(&sumsq[tid * 2 + 1], ay);
}

__global__ void k_scale(const float* __restrict__ pooled, const float* __restrict__ sumsq,
                        float* __restrict__ out, int total) {
    int i = blockIdx.x * blockDim.x + threadIdx.x;
    int base = i * 4;
    if (base < total) {
        float4 v = *(const float4*)&pooled[base];
        int col = base & 511;
        v.x /= (sqrtf(sumsq[col + 0]) + 1e-6f);
        v.y /= (sqrtf(sumsq[col + 1]) + 1e-6f);
        v.z /= (sqrtf(sumsq[col + 2]) + 1e-6f);
        v.w /= (sqrtf(sumsq[col + 3]) + 1e-6f);
        *(float4*)&out[base] = v;
    }
}

// ---------------------------------------------------------------------------
extern "C" void kernel_launch(void* const* d_in, const int* in_sizes, int n_in,
                              void* d_out, int out_size, void* d_ws, size_t ws_size,
                              hipStream_t stream) {
    const float* x0      = (const float*)d_in[0];
    const int*   ei      = (const int*)d_in[1];
    const int*   cluster = (const int*)d_in[2];
    const float* w1_[3] = {(const float*)d_in[3], (const float*)d_in[7],  (const float*)d_in[11]};
    const float* b1_[3] = {(const float*)d_in[4], (const float*)d_in[8],  (const float*)d_in[12]};
    const float* w2_[3] = {(const float*)d_in[5], (const float*)d_in[9],  (const float*)d_in[13]};
    const float* b2_[3] = {(const float*)d_in[6], (const float*)d_in[10], (const float*)d_in[14]};

    const int N  = in_sizes[2];       // 50000
    const int E  = in_sizes[1] / 2;   // 800000
    const int NC = 2500;
    float* out = (float*)d_out;

    char* p = (char*)d_ws;
    auto alloc = [&](size_t bytes) -> char* {
        char* r = p;
        p += (bytes + 255) & ~(size_t)255;
        return r;
    };
    bfu* X0hi = (bfu*)alloc((size_t)N * 64 * 2);
    bfu* X0lo = (bfu*)alloc((size_t)N * 64 * 2);
    bfu* X1hi = (bfu*)alloc((size_t)N * 128 * 2);
    bfu* X1lo = (bfu*)alloc((size_t)N * 128 * 2);
    bfu* X2hi = (bfu*)alloc((size_t)N * 256 * 2);
    bfu* X2lo = (bfu*)alloc((size_t)N * 256 * 2);
    bfu* X3hi = (bfu*)alloc((size_t)N * 512 * 2);
    bfu* w1t_hi[3]; bfu* w1t_lo[3]; bfu* w2t_hi[3]; bfu* w2t_lo[3];
    const int Ks[3] = {64, 128, 256};
    for (int l = 0; l < 3; l++) {
        w1t_hi[l] = (bfu*)alloc((size_t)64 * Ks[l] * 2);
        w1t_lo[l] = (bfu*)alloc((size_t)64 * Ks[l] * 2);
        w2t_hi[l] = (bfu*)alloc((size_t)Ks[l] * 64 * 2);
        w2t_lo[l] = (bfu*)alloc((size_t)Ks[l] * 64 * 2);
    }
    float* pooled = (float*)alloc((size_t)NC * 512 * 4);
    float* sumsq  = (float*)alloc(512 * 4);
    int*   deg    = (int*)alloc((size_t)(N + 1) * 4);
    int*   rowptr = (int*)alloc((size_t)(N + 1) * 4);
    int*   rank   = (int*)alloc((size_t)E * 4);
    int*   colidx = (int*)alloc((size_t)E * 4);
    int*   cdeg   = (int*)alloc((size_t)(NC + 1) * 4);
    int*   cptr   = (int*)alloc((size_t)(NC + 1) * 4);
    int*   crank  = (int*)alloc((size_t)N * 4);
    int*   cidx   = (int*)alloc((size_t)N * 4);
    int*   scn0   = (int*)alloc((size_t)N * 4);
    int*   scn1   = (int*)alloc((size_t)NC * 4);
    int*   bsum0  = (int*)alloc(256 * 4);
    int*   bsum1  = (int*)alloc(256 * 4);

    const int* src = ei;
    const int* dst = ei + E;

    // fused init: zeros + weight transposes + x0 conversion
    InitArgs ia;
    ia.deg = deg; ia.N = N; ia.cdeg = cdeg; ia.NC = NC; ia.sumsq = sumsq;
    for (int l = 0; l < 3; l++) {
        ia.w[2 * l]     = w1_[l]; ia.whi[2 * l]     = w1t_hi[l]; ia.wlo[2 * l]     = w1t_lo[l];
        ia.K[2 * l]     = Ks[l];  ia.Nw[2 * l]      = 64;
        ia.w[2 * l + 1] = w2_[l]; ia.whi[2 * l + 1] = w2t_hi[l]; ia.wlo[2 * l + 1] = w2t_lo[l];
        ia.K[2 * l + 1] = 64;     ia.Nw[2 * l + 1]  = Ks[l];
    }
    ia.x0 = x0; ia.xhi = X0hi; ia.xlo = X0lo; ia.xtotal = N * 64;
    k_init<<<dim3(128, 8), 256, 0, stream>>>(ia);

    // rank-recording histograms
    k_rank<<<(E + 1023) / 1024, 256, 0, stream>>>(dst, E, deg, rank, cluster, N, cdeg, crank);

    // hierarchical exclusive scan (2 phases; C scans block sums inline)
    const int nb0 = (N + 255) / 256;
    const int nb1 = (NC + 255) / 256;
    k_scanA<<<dim3(nb0, 2), 256, 0, stream>>>(deg, N, cdeg, NC, scn0, scn1, bsum0, bsum1);
    k_scanC<<<dim3(nb0, 2), 256, 0, stream>>>(deg, N, cdeg, NC, scn0, scn1, bsum0, nb0, bsum1, nb1,
                                              rowptr, cptr);

    // atomic-free scatters
    k_scatter2<<<(E + 1023) / 1024, 256, 0, stream>>>(dst, src, rank, rowptr, E, colidx,
                                                      cluster, crank, cptr, N, cidx);

    const int Mt = (N + 63) / 64;
    const int aggBlocks = (N * 64 + 255) / 256;

    // layer 0: c=64
    k_layer<true><<<Mt, 256, 0, stream>>>(X0hi, X0lo, w1t_hi[0], w1t_lo[0], b1_[0],
                                          w2t_hi[0], w2t_lo[0], b2_[0], X1hi, X1lo,
                                          N, 64, 64, 64, 128);
    k_agg<1><<<aggBlocks, 256, 0, stream>>>(X1hi, X1hi, rowptr, colidx, N, 128);

    // layer 1: c=128  (Alo for k>=64 structurally zero)
    k_layer<true><<<Mt, 256, 0, stream>>>(X1hi, X1lo, w1t_hi[1], w1t_lo[1], b1_[1],
                                          w2t_hi[1], w2t_lo[1], b2_[1], X2hi, X2lo,
                                          N, 128, 64, 128, 256);
    k_agg<2><<<aggBlocks, 256, 0, stream>>>(X2hi, X2hi, rowptr, colidx, N, 256);

    // layer 2: c=256  (Alo for k>=128 structurally zero; X3 lo plane dropped)
    k_layer<false><<<Mt, 256, 0, stream>>>(X2hi, X2lo, w1t_hi[2], w1t_lo[2], b1_[2],
                                           w2t_hi[2], w2t_lo[2], b2_[2], X3hi, nullptr,
                                           N, 256, 128, 256, 512);
    k_agg<4><<<aggBlocks, 256, 0, stream>>>(X3hi, X3hi, rowptr, colidx, N, 512);

    // cluster max-pool + column norm
    k_pool<<<NC, 256, 0, stream>>>(X3hi, cptr, cidx, pooled);
    k_sumsq<<<64, 256, 0, stream>>>(pooled, sumsq, NC);
    k_scale<<<(out_size / 4 + 255) / 256, 256, 0, stream>>>(pooled, sumsq, out, out_size);
}